// Round 1
// baseline (377.987 us; speedup 1.0000x reference)
//
#include <hip/hip_runtime.h>

// Problem constants (from reference setup_inputs): K=8, B=32, N=4096, D=64
#define ROWS_TOTAL (32 * 4096)   // B*N = 131072 rows
#define KCAND 8
// D=64 floats per row = 16 float4 chunks; 16 lanes/row, 1 float4 each.

__global__ __launch_bounds__(256) void param_distance_kernel(
    const float* __restrict__ tensor,        // [B,N,D]    = [ROWS_TOTAL, 64]
    const float* __restrict__ agg,           // [K,B,N,D]  = [K, ROWS_TOTAL, 64]
    float* __restrict__ out)                 // [1,B,N,1]  = [ROWS_TOTAL]
{
    const int tid = blockIdx.x * blockDim.x + threadIdx.x;
    const int row = tid >> 4;   // 16 lanes per row
    const int sub = tid & 15;   // float4 chunk index within row

    // All indices fit in int: agg has 16,777,216 float4 chunks total (< 2^31).
    const float4* __restrict__ t4 = (const float4*)tensor;
    const float4* __restrict__ a4 = (const float4*)agg;

    const int base = row * 16 + sub;
    const float4 t = t4[base];

    const int kstride = ROWS_TOTAL * 16;  // float4 chunks per candidate slab

    float best  = 3.402823466e+38f;  // FLT_MAX
    float bestv = 0.0f;

#pragma unroll
    for (int k = 0; k < KCAND; ++k) {
        const float4 a = a4[base + k * kstride];
        // lane sub==0 holds agg[k,row,0] in a.x — candidate gather value
        const float v0 = a.x;
        float s = fabsf(t.x - a.x) + fabsf(t.y - a.y) +
                  fabsf(t.z - a.z) + fabsf(t.w - a.w);
        // reduce across the 16 lanes of this row (xor tree stays in-group)
        s += __shfl_xor(s, 1);
        s += __shfl_xor(s, 2);
        s += __shfl_xor(s, 4);
        s += __shfl_xor(s, 8);
        // strict < with ascending k == first-occurrence argmin
        if (s < best) { best = s; bestv = v0; }
    }

    if (sub == 0) out[row] = bestv;
}

extern "C" void kernel_launch(void* const* d_in, const int* in_sizes, int n_in,
                              void* d_out, int out_size, void* d_ws, size_t ws_size,
                              hipStream_t stream) {
    const float* tensor = (const float*)d_in[0];   // [32,4096,64]
    const float* agg    = (const float*)d_in[1];   // [8,32,4096,64]
    float* out = (float*)d_out;                    // [1,32,4096,1] = 131072 floats

    // 16 lanes per row * 131072 rows = 2,097,152 threads; 256/block -> 8192 blocks
    const int threads = 256;
    const int blocks  = (ROWS_TOTAL * 16) / threads;  // 8192
    param_distance_kernel<<<blocks, threads, 0, stream>>>(tensor, agg, out);
}

// Round 2
// 375.475 us; speedup vs baseline: 1.0067x; 1.0067x over previous
//
#include <hip/hip_runtime.h>

// Problem constants: K=8, B=32, N=4096, D=64
#define ROWS_TOTAL (32 * 4096)   // B*N = 131072 rows
#define KCAND 8

// 16 lanes per row-PAIR: each thread owns one float4 chunk of TWO consecutive
// rows -> 18 independent 16B loads in flight per thread (2 tensor + 16 agg),
// double the MLP of the 1-row variant, half the total waves.
__global__ __launch_bounds__(256) void param_distance_kernel(
    const float* __restrict__ tensor,        // [ROWS_TOTAL, 64]
    const float* __restrict__ agg,           // [K, ROWS_TOTAL, 64]
    float* __restrict__ out)                 // [ROWS_TOTAL]
{
    const int tid  = blockIdx.x * blockDim.x + threadIdx.x;
    const int pair = tid >> 4;   // rows 2*pair and 2*pair+1
    const int sub  = tid & 15;   // float4 chunk within row

    const float4* __restrict__ t4 = (const float4*)tensor;
    const float4* __restrict__ a4 = (const float4*)agg;

    const int row0  = pair * 2;
    const int base0 = row0 * 16 + sub;
    const int base1 = base0 + 16;

    const float4 T0 = t4[base0];
    const float4 T1 = t4[base1];

    const int kstride = ROWS_TOTAL * 16;  // float4 chunks per candidate slab

    float best0 = 3.402823466e+38f, best1 = 3.402823466e+38f;
    float v0b = 0.0f, v1b = 0.0f;

#pragma unroll
    for (int k = 0; k < KCAND; ++k) {
        const float4 A0 = a4[base0 + k * kstride];
        const float4 A1 = a4[base1 + k * kstride];
        const float g0 = A0.x;  // lane sub==0 holds agg[k,row0,0]
        const float g1 = A1.x;  // lane sub==0 holds agg[k,row1,0]

        float s0 = fabsf(T0.x - A0.x) + fabsf(T0.y - A0.y) +
                   fabsf(T0.z - A0.z) + fabsf(T0.w - A0.w);
        float s1 = fabsf(T1.x - A1.x) + fabsf(T1.y - A1.y) +
                   fabsf(T1.z - A1.z) + fabsf(T1.w - A1.w);

        // interleaved 16-lane xor reductions (independent chains for ILP)
        s0 += __shfl_xor(s0, 1);  s1 += __shfl_xor(s1, 1);
        s0 += __shfl_xor(s0, 2);  s1 += __shfl_xor(s1, 2);
        s0 += __shfl_xor(s0, 4);  s1 += __shfl_xor(s1, 4);
        s0 += __shfl_xor(s0, 8);  s1 += __shfl_xor(s1, 8);

        // strict < with ascending k == first-occurrence argmin
        if (s0 < best0) { best0 = s0; v0b = g0; }
        if (s1 < best1) { best1 = s1; v1b = g1; }
    }

    if (sub == 0) {
        out[row0]     = v0b;
        out[row0 + 1] = v1b;
    }
}

extern "C" void kernel_launch(void* const* d_in, const int* in_sizes, int n_in,
                              void* d_out, int out_size, void* d_ws, size_t ws_size,
                              hipStream_t stream) {
    const float* tensor = (const float*)d_in[0];   // [32,4096,64]
    const float* agg    = (const float*)d_in[1];   // [8,32,4096,64]
    float* out = (float*)d_out;                    // 131072 floats

    // (ROWS_TOTAL/2) row-pairs * 16 lanes = 1,048,576 threads -> 4096 blocks
    const int threads = 256;
    const int blocks  = (ROWS_TOTAL / 2 * 16) / threads;  // 4096
    param_distance_kernel<<<blocks, threads, 0, stream>>>(tensor, agg, out);
}